// Round 2
// baseline (863.909 us; speedup 1.0000x reference)
//
#include <hip/hip_runtime.h>
#include <cstdint>
#include <cstddef>

#define N_ROWS 16384
#define K_CODES 8192
#define D_DIM 256
#define BN 128
#define BK 128
#define BD 32
#define KSPLIT 8
#define KSLICE (K_CODES / KSPLIT)   /* 1024 */
#define NT_TILES (KSLICE / BK)      /* 8 */
#define LDS_STRIDE 132              /* 128 + 4 pad: bank = (4d + r) & 31 */

// ws layout (bytes):
//   [0,      131072)  ws_min : 16384 x u64 packed (score_bits<<32 | idx)
//   [131072, 196608)  z2     : 16384 x f32
//   [196608, 229376)  e2     : 8192  x f32
//   [229376, 231424)  partials: 256 x f64 loss partial sums

__global__ __launch_bounds__(256) void k_prep(const float* __restrict__ z,
                                              const float* __restrict__ e,
                                              float* __restrict__ z2,
                                              float* __restrict__ e2,
                                              unsigned long long* __restrict__ wmin,
                                              double* __restrict__ partials) {
    int tid = threadIdx.x;
    int w = tid >> 6, lane = tid & 63;
    int row = blockIdx.x * 4 + w;
    if (blockIdx.x == 0) partials[tid] = 0.0;
    const float* src = (row < N_ROWS) ? (z + (size_t)row * D_DIM)
                                      : (e + (size_t)(row - N_ROWS) * D_DIM);
    float4 v = reinterpret_cast<const float4*>(src)[lane];
    float s = v.x * v.x;
    s = fmaf(v.y, v.y, s);
    s = fmaf(v.z, v.z, s);
    s = fmaf(v.w, v.w, s);
    #pragma unroll
    for (int off = 32; off >= 1; off >>= 1) s += __shfl_down(s, off);
    if (lane == 0) {
        if (row < N_ROWS) { z2[row] = s; wmin[row] = ~0ull; }
        else               e2[row - N_ROWS] = s;
    }
}

__global__ __launch_bounds__(256) void k_argmin(const float* __restrict__ z,
                                                const float* __restrict__ e,
                                                const float* __restrict__ z2,
                                                const float* __restrict__ e2,
                                                unsigned long long* __restrict__ wmin) {
    __shared__ float zs[BD][LDS_STRIDE];
    __shared__ float es[BD][LDS_STRIDE];
    const int tid = threadIdx.x;
    const int ty = tid >> 4, tx = tid & 15;
    const int row0 = blockIdx.x * BN;
    const int k0 = blockIdx.y * KSLICE;

    float z2r[8];
    #pragma unroll
    for (int i = 0; i < 8; i++) z2r[i] = z2[row0 + ty * 8 + i];

    float rmin[8];
    int ridx[8];
    #pragma unroll
    for (int i = 0; i < 8; i++) { rmin[i] = INFINITY; ridx[i] = 0; }

    for (int kt = 0; kt < NT_TILES; kt++) {
        const int kbase = k0 + kt * BK;
        float acc[8][8];
        #pragma unroll
        for (int i = 0; i < 8; i++)
            #pragma unroll
            for (int j = 0; j < 8; j++) acc[i][j] = 0.f;

        for (int dc = 0; dc < D_DIM; dc += BD) {
            __syncthreads();
            // stage 128 rows x 32 d of both z-tile and e-tile, transposed: [d][row]
            #pragma unroll
            for (int i = 0; i < 4; i++) {
                int li = tid * 4 + i;          // 0..1023
                int r = li >> 3;               // 0..127
                int d0 = (li & 7) * 4;         // 0..28
                float4 vz = *reinterpret_cast<const float4*>(
                    z + (size_t)(row0 + r) * D_DIM + dc + d0);
                zs[d0 + 0][r] = vz.x; zs[d0 + 1][r] = vz.y;
                zs[d0 + 2][r] = vz.z; zs[d0 + 3][r] = vz.w;
                float4 ve = *reinterpret_cast<const float4*>(
                    e + (size_t)(kbase + r) * D_DIM + dc + d0);
                es[d0 + 0][r] = ve.x; es[d0 + 1][r] = ve.y;
                es[d0 + 2][r] = ve.z; es[d0 + 3][r] = ve.w;
            }
            __syncthreads();

            #pragma unroll 2
            for (int d = 0; d < BD; d++) {
                float4 za = *reinterpret_cast<const float4*>(&zs[d][ty * 8]);
                float4 zb = *reinterpret_cast<const float4*>(&zs[d][ty * 8 + 4]);
                float4 ea = *reinterpret_cast<const float4*>(&es[d][tx * 8]);
                float4 eb = *reinterpret_cast<const float4*>(&es[d][tx * 8 + 4]);
                float zr[8] = {za.x, za.y, za.z, za.w, zb.x, zb.y, zb.z, zb.w};
                float er[8] = {ea.x, ea.y, ea.z, ea.w, eb.x, eb.y, eb.z, eb.w};
                #pragma unroll
                for (int i = 0; i < 8; i++)
                    #pragma unroll
                    for (int j = 0; j < 8; j++)
                        acc[i][j] = fmaf(zr[i], er[j], acc[i][j]);
            }
        }

        // epilogue: emulate reference rounding: R( R(z2+e2) - 2*ze )
        float e2c[8];
        #pragma unroll
        for (int j = 0; j < 8; j++) e2c[j] = e2[kbase + tx * 8 + j];
        #pragma unroll
        for (int i = 0; i < 8; i++) {
            #pragma unroll
            for (int j = 0; j < 8; j++) {
                float C = z2r[i] + e2c[j];            // R(z2+e2)
                float s = fmaf(-2.0f, acc[i][j], C);  // single rounding, == ref subtract
                if (s < rmin[i]) { rmin[i] = s; ridx[i] = kbase + tx * 8 + j; }
            }
        }
    }

    // merge across the 16 tx lanes sharing the same rows, then one atomic per row
    #pragma unroll
    for (int i = 0; i < 8; i++) {
        unsigned long long key =
            ((unsigned long long)__float_as_uint(rmin[i]) << 32) | (unsigned)ridx[i];
        #pragma unroll
        for (int m = 8; m >= 1; m >>= 1) {
            unsigned long long o = __shfl_xor(key, m);
            if (o < key) key = o;
        }
        if (tx == 0) atomicMin(wmin + row0 + ty * 8 + i, key);
    }
}

__global__ __launch_bounds__(64) void k_gather(const float* __restrict__ z,
                                               const float* __restrict__ e,
                                               const unsigned long long* __restrict__ wmin,
                                               float* __restrict__ out,
                                               double* __restrict__ partials) {
    int row = blockIdx.x;
    int lane = threadIdx.x;
    unsigned idx = (unsigned)(wmin[row] & 0xFFFFFFFFull);
    float4 q = reinterpret_cast<const float4*>(e + (size_t)idx * D_DIM)[lane];
    float4 zv = reinterpret_cast<const float4*>(z + (size_t)row * D_DIM)[lane];
    // straight-through emulation: out = z_e + R(z_q - z_e), elementwise fp32
    float dx = q.x - zv.x, dy = q.y - zv.y, dz = q.z - zv.z, dw = q.w - zv.w;
    float4 o;
    o.x = zv.x + dx; o.y = zv.y + dy; o.z = zv.z + dz; o.w = zv.w + dw;
    reinterpret_cast<float4*>(out + (size_t)row * D_DIM)[lane] = o;
    float s = dx * dx;
    s = fmaf(dy, dy, s);
    s = fmaf(dz, dz, s);
    s = fmaf(dw, dw, s);
    #pragma unroll
    for (int off = 32; off >= 1; off >>= 1) s += __shfl_down(s, off);
    if (lane == 0) atomicAdd(&partials[row & 255], (double)s);
}

__global__ __launch_bounds__(64) void k_finalize(const double* __restrict__ partials,
                                                 float* __restrict__ out_loss) {
    int lane = threadIdx.x;
    double v = partials[lane] + partials[lane + 64] +
               partials[lane + 128] + partials[lane + 192];
    #pragma unroll
    for (int off = 32; off >= 1; off >>= 1) v += __shfl_down(v, off);
    if (lane == 0) {
        float L = (float)(v / (double)((size_t)N_ROWS * D_DIM));
        out_loss[0] = L + 0.25f * L;   // mean + COMMITMENT_COST * mean
    }
}

extern "C" void kernel_launch(void* const* d_in, const int* in_sizes, int n_in,
                              void* d_out, int out_size, void* d_ws, size_t ws_size,
                              hipStream_t stream) {
    const float* z = (const float*)d_in[0];   // [16384, 256]
    const float* e = (const float*)d_in[1];   // [8192, 256]
    float* out = (float*)d_out;               // 4194304 z_q_st + 1 loss
    char* ws = (char*)d_ws;
    unsigned long long* wmin = (unsigned long long*)ws;
    float* z2 = (float*)(ws + 131072);
    float* e2 = (float*)(ws + 196608);
    double* partials = (double*)(ws + 229376);

    k_prep<<<(N_ROWS + K_CODES) / 4, 256, 0, stream>>>(z, e, z2, e2, wmin, partials);
    dim3 grid(N_ROWS / BN, KSPLIT);
    k_argmin<<<grid, 256, 0, stream>>>(z, e, z2, e2, wmin);
    k_gather<<<N_ROWS, 64, 0, stream>>>(z, e, wmin, out, partials);
    k_finalize<<<1, 64, 0, stream>>>(partials, out + (size_t)N_ROWS * D_DIM);
}